// Round 6
// baseline (290.237 us; speedup 1.0000x reference)
//
#include <hip/hip_runtime.h>

// pred/target: (B=2, C=1, H=192, W=192, D=192) fp32, D contiguous.
// 5x5x5 box mean (zero pad), ncc = cross^2/(vi*vj+1e-5), loss = -mean(ncc).
#define HH 192
#define WW 192
#define DD 192
#define BB 2
#define WWDD (WW * DD)
#define HCHUNK 28
#define NSLAB 7              // 7*28 = 196 >= 192; grid 12*12*14 = 2016 blocks
#define SLICES (HCHUNK + 4)  // 32, even -> unroll-2 folds buffer parity

// LDS stream layout (bytes), double-buffered. One slice of d-summed rows:
//   quad part (sI,sJ,sII,sJJ) : 20 rows x 17 float4 (stride 272 B)  -> 5440 B
//   IJ part                   : 20 rows x 18 floats (stride 72 B)   -> 1440 B
#define QROW 272
#define QSIZE (20 * QROW)
#define IJOFF QSIZE
#define IJROW 72
#define BUFSZ (QSIZE + 20 * IJROW)   // 6880
#define LDS_BYTES (2 * BUFSZ)        // 13760

__global__ __launch_bounds__(256, 8)
void lncc_fused_kernel(const float* __restrict__ pred,
                       const float* __restrict__ targ,
                       double* __restrict__ acc_out) {
    __shared__ alignas(16) char lds[LDS_BYTES];
    __shared__ float wpart[4];

    const int tx = threadIdx.x, ty = threadIdx.y;
    const int tid = ty * 16 + tx;

    const int d0 = blockIdx.x * 16;
    const int w0 = blockIdx.y * 16;
    const int bz = blockIdx.z;
    const int b  = bz / NSLAB;
    const int h0 = (bz - b * NSLAB) * HCHUNK;
    const int base = b * (HH * WWDD);

    // ---- producer map: 160 threads, one w-row (k) x one d-pair (dx) ----
    // Loads its own 6-float window [sdb .. sdb+5] of p and t (3 x float2,
    // 8B-aligned; neighbor overlap hits L1), computes d-summed quantities
    // in registers, writes streams. No raw-slice LDS, no d-phase.
    const int k  = tid >> 3;          // row 0..19  (w = w0-2+k)
    const int dx = tid & 7;           // outputs d = d0+2dx, d0+2dx+1
    const int sw  = w0 - 2 + k;
    const int sdb = d0 + 2 * dx - 2;
    const bool prod   = (tid < 160);
    const bool row_ok = prod && ((unsigned)sw < (unsigned)WW);
    const bool ok0 = row_ok && (sdb >= 0);         // floats sdb, sdb+1
    const bool ok1 = row_ok;                       // sdb+2..3 always in-range
    const bool ok2 = row_ok && (sdb + 5 < DD);     // floats sdb+4, sdb+5
    const int  gofs = base + sw * DD + sdb;        // deref only when masked ok
    char* const qW  = lds + (k * QROW + dx * 32);
    char* const ijW = lds + (IJOFF + k * IJROW + dx * 8);

    // ---- consumer read bases (imm offsets cover rows and buffer parity) ----
    const char* const qR  = lds + (ty * QROW + tx * 16);
    const char* const ijR = lds + (IJOFF + ty * IJROW + tx * 4);

    // h ring (last 5 d/w-summed values) + running h-sums
    float ring[5][5];
    float hs0 = 0.f, hs1 = 0.f, hs2 = 0.f, hs3 = 0.f, hs4 = 0.f;
#pragma unroll
    for (int q = 0; q < 5; ++q)
#pragma unroll
        for (int i = 0; i < 5; ++i) ring[q][i] = 0.f;
    float acc = 0.f;

    float2 P0, P1, P2, T0, T1, T2;
    auto load_slice = [&](int h) {
        P0 = P1 = P2 = T0 = T1 = T2 = make_float2(0.f, 0.f);
        if ((unsigned)h < (unsigned)HH) {
            const float* pp = pred + (gofs + h * WWDD);
            const float* tt = targ + (gofs + h * WWDD);
            if (ok0) { P0 = *(const float2*)pp;       T0 = *(const float2*)tt; }
            if (ok1) { P1 = *(const float2*)(pp + 2); T1 = *(const float2*)(tt + 2); }
            if (ok2) { P2 = *(const float2*)(pp + 4); T2 = *(const float2*)(tt + 4); }
        }
    };

    load_slice(h0 - 2);   // prefetch slice 0

#pragma unroll 2
    for (int it = 0; it < SLICES; ++it) {
        const int buf = (it & 1) * BUFSZ;

        // ---- produce: d-sums in registers -> stream writes ----
        if (prod) {
            const float p0 = P0.x, p1 = P0.y, p2 = P1.x, p3 = P1.y, p4 = P2.x, p5 = P2.y;
            const float q0 = T0.x, q1 = T0.y, q2 = T1.x, q3 = T1.y, q4 = T2.x, q5 = T2.y;
            const float ea0 = p0 + p1 + p2 + p3 + p4,             eb0 = ea0 - p0 + p5;
            const float ea1 = q0 + q1 + q2 + q3 + q4,             eb1 = ea1 - q0 + q5;
            const float pp0 = p0 * p0, pp5 = p5 * p5;
            const float qq0 = q0 * q0, qq5 = q5 * q5;
            const float pq0 = p0 * q0, pq5 = p5 * q5;
            const float ea2 = pp0 + p1*p1 + p2*p2 + p3*p3 + p4*p4, eb2 = ea2 - pp0 + pp5;
            const float ea3 = qq0 + q1*q1 + q2*q2 + q3*q3 + q4*q4, eb3 = ea3 - qq0 + qq5;
            const float ea4 = pq0 + p1*q1 + p2*q2 + p3*q3 + p4*q4, eb4 = ea4 - pq0 + pq5;
            *(float4*)(qW + buf)      = make_float4(ea0, ea1, ea2, ea3);
            *(float4*)(qW + buf + 16) = make_float4(eb0, eb1, eb2, eb3);
            *(float2*)(ijW + buf)     = make_float2(ea4, eb4);
        }

        // ---- prefetch next slice (in flight across the barrier) ----
        if (it + 1 < SLICES) load_slice(h0 - 1 + it);

        __syncthreads();

        // ---- consume: 5 b128 + 5 b32 reads -> w-sum -> h ring -> emit ----
        const char* rq = qR + buf;
        const float4 Q0 = *(const float4*)(rq);
        const float4 Q1 = *(const float4*)(rq + QROW);
        const float4 Q2 = *(const float4*)(rq + 2 * QROW);
        const float4 Q3 = *(const float4*)(rq + 3 * QROW);
        const float4 Q4 = *(const float4*)(rq + 4 * QROW);
        const char* ri = ijR + buf;
        const float An0 = Q0.x + Q1.x + Q2.x + Q3.x + Q4.x;
        const float An1 = Q0.y + Q1.y + Q2.y + Q3.y + Q4.y;
        const float An2 = Q0.z + Q1.z + Q2.z + Q3.z + Q4.z;
        const float An3 = Q0.w + Q1.w + Q2.w + Q3.w + Q4.w;
        const float An4 = *(const float*)(ri)
                        + *(const float*)(ri + IJROW)
                        + *(const float*)(ri + 2 * IJROW)
                        + *(const float*)(ri + 3 * IJROW)
                        + *(const float*)(ri + 4 * IJROW);

        hs0 += An0 - ring[0][0];
        hs1 += An1 - ring[1][0];
        hs2 += An2 - ring[2][0];
        hs3 += An3 - ring[3][0];
        hs4 += An4 - ring[4][0];
#pragma unroll
        for (int q = 0; q < 5; ++q)
#pragma unroll
            for (int i = 0; i < 4; ++i) ring[q][i] = ring[q][i + 1];
        ring[0][4] = An0; ring[1][4] = An1; ring[2][4] = An2;
        ring[3][4] = An3; ring[4][4] = An4;

        if (it >= 4) {
            const int hout = h0 + it - 4;
            if (hout < HH) {
                const float inv = 1.0f / 125.0f;
                const float uI = hs0 * inv, uJ = hs1 * inv;
                const float I2 = hs2 * inv, J2 = hs3 * inv, IJ = hs4 * inv;
                const float cross = IJ - uI * uJ;
                const float vi = I2 - uI * uI;
                const float vj = J2 - uJ * uJ;
                acc += (cross * cross) * __builtin_amdgcn_rcpf(vi * vj + 1e-5f);
            }
        }
        // single barrier per slice: reads of `buf` finish before barrier(it+1);
        // writes to `buf` recur only after barrier(it+1)  -> safe (double buffer)
    }

    // ---- block reduction, one double atomic per block ----
#pragma unroll
    for (int off = 32; off > 0; off >>= 1) acc += __shfl_down(acc, off, 64);
    const int wid = tid >> 6, lane = tid & 63;
    if (lane == 0) wpart[wid] = acc;
    __syncthreads();
    if (tid == 0)
        atomicAdd(acc_out, (double)(wpart[0] + wpart[1] + wpart[2] + wpart[3]));
}

__global__ void lncc_finalize_kernel(const double* __restrict__ acc,
                                     float* __restrict__ out) {
    const double n = (double)BB * HH * WW * DD;
    out[0] = (float)(-acc[0] / n);
}

extern "C" void kernel_launch(void* const* d_in, const int* in_sizes, int n_in,
                              void* d_out, int out_size, void* d_ws, size_t ws_size,
                              hipStream_t stream) {
    const float* pred = (const float*)d_in[0];
    const float* targ = (const float*)d_in[1];
    float* out = (float*)d_out;
    double* acc = (double*)d_ws;

    hipMemsetAsync(d_ws, 0, sizeof(double), stream);

    dim3 grid(DD / 16, WW / 16, BB * NSLAB);   // 12 x 12 x 14 = 2016 blocks
    dim3 block(16, 16, 1);                     // 256 threads
    lncc_fused_kernel<<<grid, block, 0, stream>>>(pred, targ, acc);
    lncc_finalize_kernel<<<1, 1, 0, stream>>>(acc, out);
}

// Round 7
// 185.741 us; speedup vs baseline: 1.5626x; 1.5626x over previous
//
#include <hip/hip_runtime.h>

// pred/target: (B=2, C=1, H=192, W=192, D=192) fp32, D contiguous.
// 5x5x5 box mean (zero pad), ncc = cross^2/(vi*vj+1e-5), loss = -mean(ncc).
#define HH 192
#define WW 192
#define DD 192
#define BB 2
#define WWDD (WW * DD)
#define HCHUNK 40
#define NSLAB 5              // 5*40 = 200 >= 192; grid 12*12*10 = 1440 blocks
#define SLICES (HCHUNK + 4)  // 44, even -> unroll-2 folds buffer parity

// LDS stream layout (bytes), double-buffered. One slice of d-summed rows:
//   quad part (sI,sJ,sII,sJJ) : 20 rows x 17 float4 (stride 272 B)  -> 5440 B
//   IJ part                   : 20 rows x 18 floats (stride 72 B)   -> 1440 B
#define QROW 272
#define QSIZE (20 * QROW)
#define IJOFF QSIZE
#define IJROW 72
#define BUFSZ (QSIZE + 20 * IJROW)   // 6880
#define LDS_BYTES (2 * BUFSZ)        // 13760

// (256,6): 80-VGPR cap. Live state ~70 regs (ring 25 + hs 5 + prefetch 12 +
// addrs). (256,8) = 64-reg cap caused 350 MB of scratch spill traffic in R6.
__global__ __launch_bounds__(256, 6)
void lncc_fused_kernel(const float* __restrict__ pred,
                       const float* __restrict__ targ,
                       double* __restrict__ acc_out) {
    __shared__ alignas(16) char lds[LDS_BYTES];
    __shared__ float wpart[4];

    const int tx = threadIdx.x, ty = threadIdx.y;
    const int tid = ty * 16 + tx;

    const int d0 = blockIdx.x * 16;
    const int w0 = blockIdx.y * 16;
    const int bz = blockIdx.z;
    const int b  = bz / NSLAB;
    const int h0 = (bz - b * NSLAB) * HCHUNK;
    const int base = b * (HH * WWDD);

    // ---- producer map: 160 threads, one w-row (k) x one d-pair (dx) ----
    // Each loads its own 6-float window (3 x float2; neighbor overlap absorbed
    // by L1/L2), computes d-sums in registers, writes streams directly.
    const int k  = tid >> 3;          // row 0..19  (w = w0-2+k)
    const int dx = tid & 7;           // outputs d = d0+2dx, d0+2dx+1
    const int sw  = w0 - 2 + k;
    const int sdb = d0 + 2 * dx - 2;
    const bool prod   = (tid < 160);
    const bool row_ok = prod && ((unsigned)sw < (unsigned)WW);
    const bool ok0 = row_ok && (sdb >= 0);         // floats sdb, sdb+1
    const bool ok1 = row_ok;                       // sdb+2..3 always in-range
    const bool ok2 = row_ok && (sdb + 5 < DD);     // floats sdb+4, sdb+5
    const int  gofs = base + sw * DD + sdb;        // deref only when masked ok
    char* const qW  = lds + (k * QROW + dx * 32);
    char* const ijW = lds + (IJOFF + k * IJROW + dx * 8);

    // ---- consumer read bases (imm offsets cover rows and buffer parity) ----
    const char* const qR  = lds + (ty * QROW + tx * 16);
    const char* const ijR = lds + (IJOFF + ty * IJROW + tx * 4);

    // h ring (last 5 d/w-summed values) + running h-sums
    float ring[5][5];
    float hs0 = 0.f, hs1 = 0.f, hs2 = 0.f, hs3 = 0.f, hs4 = 0.f;
#pragma unroll
    for (int q = 0; q < 5; ++q)
#pragma unroll
        for (int i = 0; i < 5; ++i) ring[q][i] = 0.f;
    float acc = 0.f;

    float2 P0, P1, P2, T0, T1, T2;
    auto load_slice = [&](int h) {
        P0 = P1 = P2 = T0 = T1 = T2 = make_float2(0.f, 0.f);
        if ((unsigned)h < (unsigned)HH) {
            const float* pp = pred + (gofs + h * WWDD);
            const float* tt = targ + (gofs + h * WWDD);
            if (ok0) { P0 = *(const float2*)pp;       T0 = *(const float2*)tt; }
            if (ok1) { P1 = *(const float2*)(pp + 2); T1 = *(const float2*)(tt + 2); }
            if (ok2) { P2 = *(const float2*)(pp + 4); T2 = *(const float2*)(tt + 4); }
        }
    };

    load_slice(h0 - 2);   // prefetch slice 0

#pragma unroll 2
    for (int it = 0; it < SLICES; ++it) {
        const int buf = (it & 1) * BUFSZ;

        // ---- produce: d-sums in registers -> stream writes ----
        if (prod) {
            const float p0 = P0.x, p1 = P0.y, p2 = P1.x, p3 = P1.y, p4 = P2.x, p5 = P2.y;
            const float q0 = T0.x, q1 = T0.y, q2 = T1.x, q3 = T1.y, q4 = T2.x, q5 = T2.y;
            const float ea0 = p0 + p1 + p2 + p3 + p4,             eb0 = ea0 - p0 + p5;
            const float ea1 = q0 + q1 + q2 + q3 + q4,             eb1 = ea1 - q0 + q5;
            const float pp0 = p0 * p0, pp5 = p5 * p5;
            const float qq0 = q0 * q0, qq5 = q5 * q5;
            const float pq0 = p0 * q0, pq5 = p5 * q5;
            const float ea2 = pp0 + p1*p1 + p2*p2 + p3*p3 + p4*p4, eb2 = ea2 - pp0 + pp5;
            const float ea3 = qq0 + q1*q1 + q2*q2 + q3*q3 + q4*q4, eb3 = ea3 - qq0 + qq5;
            const float ea4 = pq0 + p1*q1 + p2*q2 + p3*q3 + p4*q4, eb4 = ea4 - pq0 + pq5;
            *(float4*)(qW + buf)      = make_float4(ea0, ea1, ea2, ea3);
            *(float4*)(qW + buf + 16) = make_float4(eb0, eb1, eb2, eb3);
            *(float2*)(ijW + buf)     = make_float2(ea4, eb4);
        }

        // ---- prefetch next slice (in flight across the barrier) ----
        if (it + 1 < SLICES) load_slice(h0 - 1 + it);

        __syncthreads();

        // ---- consume: 5 b128 + 5 b32 reads -> w-sum -> h ring -> emit ----
        const char* rq = qR + buf;
        const float4 Q0 = *(const float4*)(rq);
        const float4 Q1 = *(const float4*)(rq + QROW);
        const float4 Q2 = *(const float4*)(rq + 2 * QROW);
        const float4 Q3 = *(const float4*)(rq + 3 * QROW);
        const float4 Q4 = *(const float4*)(rq + 4 * QROW);
        const char* ri = ijR + buf;
        const float An0 = Q0.x + Q1.x + Q2.x + Q3.x + Q4.x;
        const float An1 = Q0.y + Q1.y + Q2.y + Q3.y + Q4.y;
        const float An2 = Q0.z + Q1.z + Q2.z + Q3.z + Q4.z;
        const float An3 = Q0.w + Q1.w + Q2.w + Q3.w + Q4.w;
        const float An4 = *(const float*)(ri)
                        + *(const float*)(ri + IJROW)
                        + *(const float*)(ri + 2 * IJROW)
                        + *(const float*)(ri + 3 * IJROW)
                        + *(const float*)(ri + 4 * IJROW);

        hs0 += An0 - ring[0][0];
        hs1 += An1 - ring[1][0];
        hs2 += An2 - ring[2][0];
        hs3 += An3 - ring[3][0];
        hs4 += An4 - ring[4][0];
#pragma unroll
        for (int q = 0; q < 5; ++q)
#pragma unroll
            for (int i = 0; i < 4; ++i) ring[q][i] = ring[q][i + 1];
        ring[0][4] = An0; ring[1][4] = An1; ring[2][4] = An2;
        ring[3][4] = An3; ring[4][4] = An4;

        if (it >= 4) {
            const int hout = h0 + it - 4;
            if (hout < HH) {
                const float inv = 1.0f / 125.0f;
                const float uI = hs0 * inv, uJ = hs1 * inv;
                const float I2 = hs2 * inv, J2 = hs3 * inv, IJ = hs4 * inv;
                const float cross = IJ - uI * uJ;
                const float vi = I2 - uI * uI;
                const float vj = J2 - uJ * uJ;
                acc += (cross * cross) * __builtin_amdgcn_rcpf(vi * vj + 1e-5f);
            }
        }
        // single barrier per slice: double-buffered streams make the next
        // barrier the write/read fence for this buffer
    }

    // ---- block reduction, one double atomic per block ----
#pragma unroll
    for (int off = 32; off > 0; off >>= 1) acc += __shfl_down(acc, off, 64);
    const int wid = tid >> 6, lane = tid & 63;
    if (lane == 0) wpart[wid] = acc;
    __syncthreads();
    if (tid == 0)
        atomicAdd(acc_out, (double)(wpart[0] + wpart[1] + wpart[2] + wpart[3]));
}

__global__ void lncc_finalize_kernel(const double* __restrict__ acc,
                                     float* __restrict__ out) {
    const double n = (double)BB * HH * WW * DD;
    out[0] = (float)(-acc[0] / n);
}

extern "C" void kernel_launch(void* const* d_in, const int* in_sizes, int n_in,
                              void* d_out, int out_size, void* d_ws, size_t ws_size,
                              hipStream_t stream) {
    const float* pred = (const float*)d_in[0];
    const float* targ = (const float*)d_in[1];
    float* out = (float*)d_out;
    double* acc = (double*)d_ws;

    hipMemsetAsync(d_ws, 0, sizeof(double), stream);

    dim3 grid(DD / 16, WW / 16, BB * NSLAB);   // 12 x 12 x 10 = 1440 blocks
    dim3 block(16, 16, 1);                     // 256 threads
    lncc_fused_kernel<<<grid, block, 0, stream>>>(pred, targ, acc);
    lncc_finalize_kernel<<<1, 1, 0, stream>>>(acc, out);
}